// Round 28
// baseline (71.014 us; speedup 1.0000x reference)
//
#include <hip/hip_runtime.h>
#include <hip/hip_bf16.h>
#include <math.h>

typedef __attribute__((ext_vector_type(8))) short bf16x8;
typedef __attribute__((ext_vector_type(4))) float f32x4;
typedef __attribute__((ext_vector_type(8))) _Float16 h8;
typedef unsigned long long u64;

#define NSAMP  128000
#define TFR    501
#define TP     512         // padded t-stride of power planes
#define FPOW   257
#define NF     257
#define B_SZ   64
#define CHUNKT 128
#define NCH    4
#define WARM   32          // alpha^32 ~ 8e-4: loss shift << threshold
#define EPS_F  1.1920928955078125e-07f

#define SEG    16640       // 64*256 + 256 samples per 64-frame chunk
#define WOFF   66560       // window table offset in LDS (2 KB)
#define LDS_TOTAL 68608
#define BGRPB  131072      // basis per parity group: 8ph x 16colgrp x 1024B
#define BPHB2  16384       // basis per phase per group

// ---- folded basis [grp(2)][ph(8)][colgrp(16)][lane(64)][8 bf16] + wtab --
// (r22/r25 mapping, HW-verified). 128 blocks x 4 cols each (launch amortize).
// Also zeroes d_out (replaces memset dispatch).
__global__ __launch_bounds__(256)
void build_basis(unsigned short* __restrict__ Bt, float* __restrict__ wtab,
                 float* __restrict__ out) {
    const int m = threadIdx.x;           // 0..255
    #pragma unroll
    for (int cc4 = 0; cc4 < 4; ++cc4) {
        const int c = blockIdx.x * 4 + cc4;  // 0..511
        const int grp = c >> 8, cc = c & 255;
        const int eo = (cc >> 5) * 16 + (cc & 15);
        const int isIm = (cc >> 4) & 1;
        const int bin = grp ? (2 * eo + 1) : (2 * eo);
        float v;
        if (grp == 0 && cc == 16) {
            v = (m & 1) ? -1.f : 1.f;        // Nyquist basis vs s_e
        } else {
            int mm = (bin * m) & 511;
            float th = (float)mm * (float)(2.0 * M_PI / 512.0);
            v = isIm ? -sinf(th) : cosf(th);
        }
        __hip_bfloat16 h = __float2bfloat16(v);
        int ph = m >> 5, cg16 = cc >> 4;
        int lane = ((m >> 3) & 3) * 16 + (cc & 15);
        size_t idx = (((size_t)(grp * 8 + ph) * 16 + cg16) * 64 + lane) * 8 + (m & 7);
        Bt[idx] = *reinterpret_cast<unsigned short*>(&h);
    }
    if (blockIdx.x == 0) {
        if (m == 0) *out = 0.f;
        wtab[m]       = sinf((float)m * (float)(M_PI / 512.0));
        wtab[m + 256] = sinf((float)(m + 256) * (float)(M_PI / 512.0));
    }
}

// ---- MFMA DFT GEMM v25 (frozen winner) ----------------------------------
__global__ __launch_bounds__(512)
void dft_gemm(const float* __restrict__ sig,
              const float* __restrict__ intf,
              const unsigned short* __restrict__ Bt,
              const float* __restrict__ wtab,
              _Float16* __restrict__ powo)
{
    extern __shared__ char As[];

    const int mchunk = blockIdx.x, b = blockIdx.y, s = blockIdx.z;
    const int tid = threadIdx.x, lane = tid & 63, wn = tid >> 6;  // 8 waves
    const int lq = lane >> 4, ll = lane & 15;
    const float* x = (s == 0 ? intf : sig) + (size_t)b * NSAMP;
    const int tbase = mchunk * 16384 - 256;

    // ---- Step 1: f32 DMA into LDS (linear), edge-clamped; + window table ---
    if (mchunk >= 1 && mchunk <= 6) {
        const char* xg = (const char*)(x + tbase);
        #pragma unroll
        for (int r = 0; r < 8; ++r) {
            int o = r * 8192 + tid * 16;
            __builtin_amdgcn_global_load_lds(
                (const __attribute__((address_space(1))) void*)(xg + o),
                (__attribute__((address_space(3))) void*)(As + o), 16, 0, 0);
        }
        if (tid < 64) {
            int o = 65536 + tid * 16;
            __builtin_amdgcn_global_load_lds(
                (const __attribute__((address_space(1))) void*)(xg + o),
                (__attribute__((address_space(3))) void*)(As + o), 16, 0, 0);
        }
    } else if (mchunk == 0) {
        const char* xg = (const char*)x;
        #pragma unroll
        for (int r = 0; r < 8; ++r) {
            int o = 1024 + r * 8192 + tid * 16;
            __builtin_amdgcn_global_load_lds(
                (const __attribute__((address_space(1))) void*)(xg + o - 1024),
                (__attribute__((address_space(3))) void*)(As + o), 16, 0, 0);
        }
    } else {  // mchunk == 7: 54272 valid bytes
        const char* xg = (const char*)(x + tbase);
        #pragma unroll
        for (int r = 0; r < 6; ++r) {
            int o = r * 8192 + tid * 16;
            __builtin_amdgcn_global_load_lds(
                (const __attribute__((address_space(1))) void*)(xg + o),
                (__attribute__((address_space(3))) void*)(As + o), 16, 0, 0);
        }
        if (tid < 320) {
            int o = 49152 + tid * 16;
            __builtin_amdgcn_global_load_lds(
                (const __attribute__((address_space(1))) void*)(xg + o),
                (__attribute__((address_space(3))) void*)(As + o), 16, 0, 0);
        }
    }
    if (tid < 128) {   // window table: 2 KB
        int o = tid * 16;
        __builtin_amdgcn_global_load_lds(
            (const __attribute__((address_space(1))) void*)((const char*)wtab + o),
            (__attribute__((address_space(3))) void*)(As + WOFF + o), 16, 0, 0);
    }

    const int grp = wn >> 2;            // 0: even bins (s_e), 1: odd (s_o)
    const int grpoff = grp * 512;
    const char* WB = (const char*)Bt + (size_t)grp * BGRPB
                   + (wn & 3) * 4096 + lane * 16;
    bf16x8 B0[4], B1[4];
    auto loadPh = [&](int ph, bf16x8 (&dst)[4]) {
        const char* bp = WB + (size_t)ph * BPHB2;
        #pragma unroll
        for (int nf = 0; nf < 4; ++nf)
            dst[nf] = *(const bf16x8*)(bp + nf * 1024);
    };
    loadPh(0, B0);

    asm volatile("s_waitcnt vmcnt(0)" ::: "memory");   // DMA + B0 landed
    __syncthreads();

    // ---- Step 2: reflect patches (LDS->LDS, disjoint) ----
    if (mchunk == 0) {
        if (tid < 256) {
            float v = *(const float*)(As + (512 - tid) * 4);
            *(float*)(As + tid * 4) = v;
        }
        __syncthreads();
    } else if (mchunk == 7) {
        #pragma unroll
        for (int q = 0; q < 6; ++q) {
            int j = 13568 + q * 512 + tid;
            float v = *(const float*)(As + (27134 - j) * 4);
            *(float*)(As + j * 4) = v;
        }
        __syncthreads();
    }

    // ---- Step 3: fold+window+convert sweep (two disjoint halves) ----
    {
        const char* wt = As + WOFF;
        #pragma unroll 1
        for (int hh = 0; hh < 2; ++hh) {
            f32x4 xa[4], xb[4];
            #pragma unroll
            for (int i = 0; i < 4; ++i) {
                int qid = i * 512 + tid;
                int row = hh * 32 + (qid >> 6);
                int mq = qid & 63;
                int ra = row * 1024 + mq * 16;
                xa[i] = *(const f32x4*)(As + ra);
                xb[i] = *(const f32x4*)(As + ra + 1024);
            }
            __syncthreads();
            #pragma unroll
            for (int i = 0; i < 4; ++i) {
                int qid = i * 512 + tid;
                int row = hh * 32 + (qid >> 6);
                int mq = qid & 63;
                f32x4 we = *(const f32x4*)(wt + mq * 16);
                f32x4 wo = *(const f32x4*)(wt + 1024 + mq * 16);
                unsigned short he[4], ho[4];
                #pragma unroll
                for (int e = 0; e < 4; ++e) {
                    float pa = xa[i][e] * we[e];
                    float pb = xb[i][e] * wo[e];
                    __hip_bfloat16 t0 = __float2bfloat16(pa + pb);
                    __hip_bfloat16 t1 = __float2bfloat16(pa - pb);
                    he[e] = *(unsigned short*)&t0;
                    ho[e] = *(unsigned short*)&t1;
                }
                int ae = row * 1024 + mq * 8;
                int ao = ae + 512;
                ae ^= ((ae >> 10) & 7) << 4;
                ao ^= ((ao >> 10) & 7) << 4;
                *(u64*)(As + ae) = (u64)he[0] | ((u64)he[1] << 16) |
                                   ((u64)he[2] << 32) | ((u64)he[3] << 48);
                *(u64*)(As + ao) = (u64)ho[0] | ((u64)ho[1] << 16) |
                                   ((u64)ho[2] << 32) | ((u64)ho[3] << 48);
            }
        }
        __syncthreads();
    }

    f32x4 acc[4][4];
    #pragma unroll
    for (int i = 0; i < 4; ++i)
        #pragma unroll
        for (int j = 0; j < 4; ++j) acc[i][j] = 0;

    auto doPhase = [&](int ph, bf16x8 (&cur)[4]) {
        bf16x8 af[4];
        #pragma unroll
        for (int mf = 0; mf < 4; ++mf) {
            int a = (mf * 16 + ll) * 1024 + grpoff + ph * 64 + lq * 16;
            a ^= ((a >> 10) & 7) << 4;
            af[mf] = *(const bf16x8*)(As + a);
        }
        __builtin_amdgcn_s_setprio(1);
        #pragma unroll
        for (int mf = 0; mf < 4; ++mf)
            #pragma unroll
            for (int nf = 0; nf < 4; ++nf)
                acc[mf][nf] = __builtin_amdgcn_mfma_f32_16x16x32_bf16(
                    af[mf], cur[nf], acc[mf][nf], 0, 0, 0);
        __builtin_amdgcn_s_setprio(0);
    };

    #pragma unroll 1
    for (int pp2 = 0; pp2 < 4; ++pp2) {
        const int ph = pp2 * 2;
        loadPh(ph + 1, B1);                 // prefetch odd phase
        doPhase(ph, B0);                    // compute even phase
        if (pp2 < 3) loadPh(ph + 2, B0);    // prefetch next even phase
        doPhase(ph + 1, B1);                // compute odd phase
    }

    // ---- epilogue: power, t-major fp16, packed u64 ----
    const int sb = s * 64 + b;
    _Float16* pbase = powo + (size_t)sb * FPOW * TP;
    #pragma unroll
    for (int mf = 0; mf < 4; ++mf) {
        const int rl0 = mchunk * 64 + mf * 16 + lq * 4;
        #pragma unroll
        for (int p = 0; p < 2; ++p) {
            f32x4 re = acc[mf][2 * p], im = acc[mf][2 * p + 1];
            int gb = (wn & 3) * 2 + p;
            int eo = gb * 16 + ll;
            int bin = grp ? (2 * eo + 1) : (2 * eo);
            bool nyq = (grp == 0) && (gb == 0) && (ll == 0);
            unsigned short hp[4], hn[4];
            #pragma unroll
            for (int j = 0; j < 4; ++j) {
                float pr = re[j] * re[j];
                float pi = im[j] * im[j];
                _Float16 hv = (_Float16)(nyq ? pr : (pr + pi));
                hp[j] = *(unsigned short*)&hv;
                _Float16 hw = (_Float16)pi;
                hn[j] = *(unsigned short*)&hw;
            }
            u64 pk = (u64)hp[0] | ((u64)hp[1] << 16) |
                     ((u64)hp[2] << 32) | ((u64)hp[3] << 48);
            *(u64*)(pbase + (size_t)bin * TP + rl0) = pk;
            if (nyq) {
                u64 pk2 = (u64)hn[0] | ((u64)hn[1] << 16) |
                          ((u64)hn[2] << 32) | ((u64)hn[3] << 48);
                *(u64*)(pbase + (size_t)256 * TP + rl0) = pk2;
            }
        }
    }
}

// ---- warm-up: vectorized fp16 loads, static indexing --------------------
template<int W>
__device__ __forceinline__ float warm_fixed(const _Float16* __restrict__ nrow,
                                            int base, float alpha, float oma) {
    h8 blk[W / 8];
    #pragma unroll
    for (int i = 0; i < W / 8; ++i)
        blk[i] = *(const h8*)(nrow + base + i * 8);
    float v = (float)blk[0][0];
    #pragma unroll
    for (int i = 1; i < W; ++i)
        v = fmaf(alpha, v, oma * (float)blk[i / 8][i % 8]);
    v = fmaf(alpha, v, oma * (float)nrow[base + W]);
    return v;
}

// ---- chunked IIR scan + SPP + MSE: CHUNKT=128, warm amortized 4x --------
// Thread = (b, c, f); chunk of 128 t's as four 32-halves sharing one warm-up.
// v carries across halves: each half's 32nd update lands on next base.
__global__ __launch_bounds__(256, 4)
void spp_loss_kernel(const _Float16* __restrict__ noiseP,
                     const _Float16* __restrict__ noisyP,
                     const float* __restrict__ est,
                     float* __restrict__ out,
                     float alpha)
{
    const double XI = 31.622776601683793;
    const float RATIO = (float)(1.0 + XI);
    const float COEF  = (float)(XI / (1.0 + XI));
    const float INVN  = (float)(1.0 / ((double)B_SZ * NF * TFR));

    int tid = blockIdx.x * blockDim.x + threadIdx.x;
    int f   = tid % NF;
    int rem = tid / NF;
    int c   = rem & (NCH - 1);
    int b   = rem >> 2;

    float local = 0.f;
    if (b < B_SZ) {
        const int t0   = c * CHUNKT;
        const int tend = min(TFR, t0 + CHUNKT);
        const _Float16* nrow = noiseP + ((size_t)b * NF + f) * TP;
        const _Float16* yrow = noisyP + ((size_t)b * NF + f) * TP;
        const float* erow = est + ((size_t)b * NF + f) * TFR;
        const float oma = 1.f - alpha;

        float v;
        if (t0 == 0) v = (float)nrow[0];
        else         v = warm_fixed<WARM>(nrow, t0 - WARM, alpha, oma);

        #pragma unroll 1
        for (int h = 0; h < 4; ++h) {
            const int hb = t0 + h * 32;        // <= 480 < TFR always
            h8 wn8[4], wy8[4];
            #pragma unroll
            for (int i = 0; i < 4; ++i) {
                wn8[i] = *(const h8*)(nrow + hb + i * 8);
                wy8[i] = *(const h8*)(yrow + hb + i * 8);
            }
            float last_n = (float)nrow[hb + 32];
            float e0;
            float qe[31];
            if (hb + 33 <= TFR) {
                e0 = erow[hb];
                #pragma unroll
                for (int i = 0; i < 8; ++i) {
                    float4 v4 = *(const float4*)(erow + hb + 1 + i * 4);
                    if (i * 4 + 0 < 31) qe[i*4+0] = v4.x;
                    if (i * 4 + 1 < 31) qe[i*4+1] = v4.y;
                    if (i * 4 + 2 < 31) qe[i*4+2] = v4.z;
                    if (i * 4 + 3 < 31) qe[i*4+3] = v4.w;
                }
            } else {
                e0 = erow[min(hb, TFR - 1)];
                #pragma unroll
                for (int i = 0; i < 31; ++i)
                    qe[i] = erow[min(hb + 1 + i, TFR - 1)];
            }

            // base emit at hb
            {
                float np = (float)wy8[0][0];
                float expo = -np / (v + EPS_F) * COEF;
                float spp  = 1.f / fmaf(RATIO, __expf(expo), 1.f);
                float d = e0 - spp;
                local = fmaf(d, d, local);
            }
            // updates hb+1 .. hb+32; emits hb+1 .. hb+31 (hb+32 is next base)
            #pragma unroll
            for (int i = 0; i < 32; ++i) {
                float nv = (i < 31) ? (float)wn8[(i + 1) / 8][(i + 1) % 8]
                                    : last_n;
                v = fmaf(alpha, v, oma * nv);
                if (i < 31) {
                    int t = hb + 1 + i;
                    if (t < tend) {
                        float yv = (float)wy8[(i + 1) / 8][(i + 1) % 8];
                        float expo = -yv / (v + EPS_F) * COEF;
                        float spp  = 1.f / fmaf(RATIO, __expf(expo), 1.f);
                        float d = qe[i] - spp;
                        local = fmaf(d, d, local);
                    }
                }
            }
        }
    }

    for (int off = 32; off > 0; off >>= 1)
        local += __shfl_down(local, off);
    __shared__ float wsum[4];
    if ((threadIdx.x & 63) == 0) wsum[threadIdx.x >> 6] = local;
    __syncthreads();
    if (threadIdx.x == 0) {
        float ssum = (wsum[0] + wsum[1]) + (wsum[2] + wsum[3]);
        atomicAdd(out, ssum * INVN);
    }
}

extern "C" void kernel_launch(void* const* d_in, const int* in_sizes, int n_in,
                              void* d_out, int out_size, void* d_ws, size_t ws_size,
                              hipStream_t stream) {
    const float* est  = (const float*)d_in[0];   // spp_estimate (B,1,F,T)
    const float* sig  = (const float*)d_in[1];   // input_sig    (B,1,N)
    const float* intf = (const float*)d_in[2];   // interference (B,1,N)

    unsigned short* Bt = (unsigned short*)d_ws;                       // 256 KB
    float* wtab = (float*)((char*)d_ws + (size_t)262144);             // 2 KB
    _Float16* powp = (_Float16*)((char*)d_ws + (size_t)512 * 1024);

    hipLaunchKernelGGL(build_basis, dim3(128), dim3(256), 0, stream,
                       Bt, wtab, (float*)d_out);

    hipFuncSetAttribute((const void*)dft_gemm,
                        hipFuncAttributeMaxDynamicSharedMemorySize, LDS_TOTAL);
    dim3 gG(8, 64, 2);
    hipLaunchKernelGGL(dft_gemm, gG, dim3(512), LDS_TOTAL, stream,
                       sig, intf, Bt, wtab, powp);

    const double alpha_d = exp(-((double)256) / (16000.0 * 0.072));
    const _Float16* noiseP = powp;                            // sb 0..63
    const _Float16* noisyP = powp + (size_t)B_SZ * FPOW * TP; // sb 64..127
    dim3 gB((B_SZ * NCH * NF + 255) / 256);
    hipLaunchKernelGGL(spp_loss_kernel, gB, dim3(256), 0, stream,
                       noiseP, noisyP, est, (float*)d_out, (float)alpha_d);
}

// Round 29
// 70.354 us; speedup vs baseline: 1.0094x; 1.0094x over previous
//
#include <hip/hip_runtime.h>
#include <hip/hip_bf16.h>
#include <math.h>

typedef __attribute__((ext_vector_type(8))) short bf16x8;
typedef __attribute__((ext_vector_type(4))) float f32x4;
typedef __attribute__((ext_vector_type(8))) _Float16 h8;
typedef unsigned long long u64;

#define NSAMP  128000
#define TFR    501
#define TP     512         // padded t-stride of power planes
#define FPOW   257
#define NF     257
#define B_SZ   64
#define CHUNKT 64
#define NCH    8
#define WARM   32          // alpha^32 ~ 8e-4: loss shift << threshold
#define EPS_F  1.1920928955078125e-07f

#define SEG    16640       // 64*256 + 256 samples per 64-frame chunk
#define WOFF   66560       // window table offset in LDS (2 KB)
#define LDS_TOTAL 68608
#define BGRPB  131072      // basis per parity group: 8ph x 16colgrp x 1024B
#define BPHB2  16384       // basis per phase per group

// ---- folded basis [grp(2)][ph(8)][colgrp(16)][lane(64)][8 bf16] + wtab --
// (r22/r25 mapping, HW-verified). 128 blocks x 4 cols each (launch amortize).
// Also zeroes d_out (replaces memset dispatch).
__global__ __launch_bounds__(256)
void build_basis(unsigned short* __restrict__ Bt, float* __restrict__ wtab,
                 float* __restrict__ out) {
    const int m = threadIdx.x;           // 0..255
    #pragma unroll
    for (int cc4 = 0; cc4 < 4; ++cc4) {
        const int c = blockIdx.x * 4 + cc4;  // 0..511
        const int grp = c >> 8, cc = c & 255;
        const int eo = (cc >> 5) * 16 + (cc & 15);
        const int isIm = (cc >> 4) & 1;
        const int bin = grp ? (2 * eo + 1) : (2 * eo);
        float v;
        if (grp == 0 && cc == 16) {
            v = (m & 1) ? -1.f : 1.f;        // Nyquist basis vs s_e
        } else {
            int mm = (bin * m) & 511;
            float th = (float)mm * (float)(2.0 * M_PI / 512.0);
            v = isIm ? -sinf(th) : cosf(th);
        }
        __hip_bfloat16 h = __float2bfloat16(v);
        int ph = m >> 5, cg16 = cc >> 4;
        int lane = ((m >> 3) & 3) * 16 + (cc & 15);
        size_t idx = (((size_t)(grp * 8 + ph) * 16 + cg16) * 64 + lane) * 8 + (m & 7);
        Bt[idx] = *reinterpret_cast<unsigned short*>(&h);
    }
    if (blockIdx.x == 0) {
        if (m == 0) *out = 0.f;
        wtab[m]       = sinf((float)m * (float)(M_PI / 512.0));
        wtab[m + 256] = sinf((float)(m + 256) * (float)(M_PI / 512.0));
    }
}

// ---- MFMA DFT GEMM v25 (frozen winner) ----------------------------------
__global__ __launch_bounds__(512)
void dft_gemm(const float* __restrict__ sig,
              const float* __restrict__ intf,
              const unsigned short* __restrict__ Bt,
              const float* __restrict__ wtab,
              _Float16* __restrict__ powo)
{
    extern __shared__ char As[];

    const int mchunk = blockIdx.x, b = blockIdx.y, s = blockIdx.z;
    const int tid = threadIdx.x, lane = tid & 63, wn = tid >> 6;  // 8 waves
    const int lq = lane >> 4, ll = lane & 15;
    const float* x = (s == 0 ? intf : sig) + (size_t)b * NSAMP;
    const int tbase = mchunk * 16384 - 256;

    // ---- Step 1: f32 DMA into LDS (linear), edge-clamped; + window table ---
    if (mchunk >= 1 && mchunk <= 6) {
        const char* xg = (const char*)(x + tbase);
        #pragma unroll
        for (int r = 0; r < 8; ++r) {
            int o = r * 8192 + tid * 16;
            __builtin_amdgcn_global_load_lds(
                (const __attribute__((address_space(1))) void*)(xg + o),
                (__attribute__((address_space(3))) void*)(As + o), 16, 0, 0);
        }
        if (tid < 64) {
            int o = 65536 + tid * 16;
            __builtin_amdgcn_global_load_lds(
                (const __attribute__((address_space(1))) void*)(xg + o),
                (__attribute__((address_space(3))) void*)(As + o), 16, 0, 0);
        }
    } else if (mchunk == 0) {
        const char* xg = (const char*)x;
        #pragma unroll
        for (int r = 0; r < 8; ++r) {
            int o = 1024 + r * 8192 + tid * 16;
            __builtin_amdgcn_global_load_lds(
                (const __attribute__((address_space(1))) void*)(xg + o - 1024),
                (__attribute__((address_space(3))) void*)(As + o), 16, 0, 0);
        }
    } else {  // mchunk == 7: 54272 valid bytes
        const char* xg = (const char*)(x + tbase);
        #pragma unroll
        for (int r = 0; r < 6; ++r) {
            int o = r * 8192 + tid * 16;
            __builtin_amdgcn_global_load_lds(
                (const __attribute__((address_space(1))) void*)(xg + o),
                (__attribute__((address_space(3))) void*)(As + o), 16, 0, 0);
        }
        if (tid < 320) {
            int o = 49152 + tid * 16;
            __builtin_amdgcn_global_load_lds(
                (const __attribute__((address_space(1))) void*)(xg + o),
                (__attribute__((address_space(3))) void*)(As + o), 16, 0, 0);
        }
    }
    if (tid < 128) {   // window table: 2 KB
        int o = tid * 16;
        __builtin_amdgcn_global_load_lds(
            (const __attribute__((address_space(1))) void*)((const char*)wtab + o),
            (__attribute__((address_space(3))) void*)(As + WOFF + o), 16, 0, 0);
    }

    const int grp = wn >> 2;            // 0: even bins (s_e), 1: odd (s_o)
    const int grpoff = grp * 512;
    const char* WB = (const char*)Bt + (size_t)grp * BGRPB
                   + (wn & 3) * 4096 + lane * 16;
    bf16x8 B0[4], B1[4];
    auto loadPh = [&](int ph, bf16x8 (&dst)[4]) {
        const char* bp = WB + (size_t)ph * BPHB2;
        #pragma unroll
        for (int nf = 0; nf < 4; ++nf)
            dst[nf] = *(const bf16x8*)(bp + nf * 1024);
    };
    loadPh(0, B0);

    asm volatile("s_waitcnt vmcnt(0)" ::: "memory");   // DMA + B0 landed
    __syncthreads();

    // ---- Step 2: reflect patches (LDS->LDS, disjoint) ----
    if (mchunk == 0) {
        if (tid < 256) {
            float v = *(const float*)(As + (512 - tid) * 4);
            *(float*)(As + tid * 4) = v;
        }
        __syncthreads();
    } else if (mchunk == 7) {
        #pragma unroll
        for (int q = 0; q < 6; ++q) {
            int j = 13568 + q * 512 + tid;
            float v = *(const float*)(As + (27134 - j) * 4);
            *(float*)(As + j * 4) = v;
        }
        __syncthreads();
    }

    // ---- Step 3: fold+window+convert sweep (two disjoint halves) ----
    {
        const char* wt = As + WOFF;
        #pragma unroll 1
        for (int hh = 0; hh < 2; ++hh) {
            f32x4 xa[4], xb[4];
            #pragma unroll
            for (int i = 0; i < 4; ++i) {
                int qid = i * 512 + tid;
                int row = hh * 32 + (qid >> 6);
                int mq = qid & 63;
                int ra = row * 1024 + mq * 16;
                xa[i] = *(const f32x4*)(As + ra);
                xb[i] = *(const f32x4*)(As + ra + 1024);
            }
            __syncthreads();
            #pragma unroll
            for (int i = 0; i < 4; ++i) {
                int qid = i * 512 + tid;
                int row = hh * 32 + (qid >> 6);
                int mq = qid & 63;
                f32x4 we = *(const f32x4*)(wt + mq * 16);
                f32x4 wo = *(const f32x4*)(wt + 1024 + mq * 16);
                unsigned short he[4], ho[4];
                #pragma unroll
                for (int e = 0; e < 4; ++e) {
                    float pa = xa[i][e] * we[e];
                    float pb = xb[i][e] * wo[e];
                    __hip_bfloat16 t0 = __float2bfloat16(pa + pb);
                    __hip_bfloat16 t1 = __float2bfloat16(pa - pb);
                    he[e] = *(unsigned short*)&t0;
                    ho[e] = *(unsigned short*)&t1;
                }
                int ae = row * 1024 + mq * 8;
                int ao = ae + 512;
                ae ^= ((ae >> 10) & 7) << 4;
                ao ^= ((ao >> 10) & 7) << 4;
                *(u64*)(As + ae) = (u64)he[0] | ((u64)he[1] << 16) |
                                   ((u64)he[2] << 32) | ((u64)he[3] << 48);
                *(u64*)(As + ao) = (u64)ho[0] | ((u64)ho[1] << 16) |
                                   ((u64)ho[2] << 32) | ((u64)ho[3] << 48);
            }
        }
        __syncthreads();
    }

    f32x4 acc[4][4];
    #pragma unroll
    for (int i = 0; i < 4; ++i)
        #pragma unroll
        for (int j = 0; j < 4; ++j) acc[i][j] = 0;

    auto doPhase = [&](int ph, bf16x8 (&cur)[4]) {
        bf16x8 af[4];
        #pragma unroll
        for (int mf = 0; mf < 4; ++mf) {
            int a = (mf * 16 + ll) * 1024 + grpoff + ph * 64 + lq * 16;
            a ^= ((a >> 10) & 7) << 4;
            af[mf] = *(const bf16x8*)(As + a);
        }
        __builtin_amdgcn_s_setprio(1);
        #pragma unroll
        for (int mf = 0; mf < 4; ++mf)
            #pragma unroll
            for (int nf = 0; nf < 4; ++nf)
                acc[mf][nf] = __builtin_amdgcn_mfma_f32_16x16x32_bf16(
                    af[mf], cur[nf], acc[mf][nf], 0, 0, 0);
        __builtin_amdgcn_s_setprio(0);
    };

    #pragma unroll 1
    for (int pp2 = 0; pp2 < 4; ++pp2) {
        const int ph = pp2 * 2;
        loadPh(ph + 1, B1);                 // prefetch odd phase
        doPhase(ph, B0);                    // compute even phase
        if (pp2 < 3) loadPh(ph + 2, B0);    // prefetch next even phase
        doPhase(ph + 1, B1);                // compute odd phase
    }

    // ---- epilogue: power, t-major fp16, packed u64 ----
    const int sb = s * 64 + b;
    _Float16* pbase = powo + (size_t)sb * FPOW * TP;
    #pragma unroll
    for (int mf = 0; mf < 4; ++mf) {
        const int rl0 = mchunk * 64 + mf * 16 + lq * 4;
        #pragma unroll
        for (int p = 0; p < 2; ++p) {
            f32x4 re = acc[mf][2 * p], im = acc[mf][2 * p + 1];
            int gb = (wn & 3) * 2 + p;
            int eo = gb * 16 + ll;
            int bin = grp ? (2 * eo + 1) : (2 * eo);
            bool nyq = (grp == 0) && (gb == 0) && (ll == 0);
            unsigned short hp[4], hn[4];
            #pragma unroll
            for (int j = 0; j < 4; ++j) {
                float pr = re[j] * re[j];
                float pi = im[j] * im[j];
                _Float16 hv = (_Float16)(nyq ? pr : (pr + pi));
                hp[j] = *(unsigned short*)&hv;
                _Float16 hw = (_Float16)pi;
                hn[j] = *(unsigned short*)&hw;
            }
            u64 pk = (u64)hp[0] | ((u64)hp[1] << 16) |
                     ((u64)hp[2] << 32) | ((u64)hp[3] << 48);
            *(u64*)(pbase + (size_t)bin * TP + rl0) = pk;
            if (nyq) {
                u64 pk2 = (u64)hn[0] | ((u64)hn[1] << 16) |
                          ((u64)hn[2] << 32) | ((u64)hn[3] << 48);
                *(u64*)(pbase + (size_t)256 * TP + rl0) = pk2;
            }
        }
    }
}

// ---- warm-up: vectorized fp16 loads, static indexing --------------------
template<int W>
__device__ __forceinline__ float warm_fixed(const _Float16* __restrict__ nrow,
                                            int base, float alpha, float oma) {
    h8 blk[W / 8];
    #pragma unroll
    for (int i = 0; i < W / 8; ++i)
        blk[i] = *(const h8*)(nrow + base + i * 8);
    float v = (float)blk[0][0];
    #pragma unroll
    for (int i = 1; i < W; ++i)
        v = fmaf(alpha, v, oma * (float)blk[i / 8][i % 8]);
    v = fmaf(alpha, v, oma * (float)nrow[base + W]);
    return v;
}

// ---- chunked IIR scan + SPP + MSE: CHUNKT=64, warm amortized 2x ---------
// (r27 winner restored: 514 blocks keeps 2 blocks/CU for latency cover.)
__global__ __launch_bounds__(256, 4)
void spp_loss_kernel(const _Float16* __restrict__ noiseP,
                     const _Float16* __restrict__ noisyP,
                     const float* __restrict__ est,
                     float* __restrict__ out,
                     float alpha)
{
    const double XI = 31.622776601683793;
    const float RATIO = (float)(1.0 + XI);
    const float COEF  = (float)(XI / (1.0 + XI));
    const float INVN  = (float)(1.0 / ((double)B_SZ * NF * TFR));

    int tid = blockIdx.x * blockDim.x + threadIdx.x;
    int f   = tid % NF;
    int rem = tid / NF;
    int c   = rem & (NCH - 1);
    int b   = rem >> 3;

    float local = 0.f;
    if (b < B_SZ) {
        const int t0   = c * CHUNKT;
        const int tend = min(TFR, t0 + CHUNKT);
        const _Float16* nrow = noiseP + ((size_t)b * NF + f) * TP;
        const _Float16* yrow = noisyP + ((size_t)b * NF + f) * TP;
        const float* erow = est + ((size_t)b * NF + f) * TFR;
        const float oma = 1.f - alpha;

        float v;
        if (t0 == 0) v = (float)nrow[0];
        else         v = warm_fixed<WARM>(nrow, t0 - WARM, alpha, oma);

        #pragma unroll
        for (int h = 0; h < 2; ++h) {
            const int hb = t0 + h * 32;
            h8 wn8[4], wy8[4];
            #pragma unroll
            for (int i = 0; i < 4; ++i) {
                wn8[i] = *(const h8*)(nrow + hb + i * 8);
                wy8[i] = *(const h8*)(yrow + hb + i * 8);
            }
            float last_n = (float)nrow[hb + 32];
            float e0;
            float qe[31];
            if (hb + 33 <= TFR) {
                e0 = erow[hb];
                #pragma unroll
                for (int i = 0; i < 8; ++i) {
                    float4 v4 = *(const float4*)(erow + hb + 1 + i * 4);
                    if (i * 4 + 0 < 31) qe[i*4+0] = v4.x;
                    if (i * 4 + 1 < 31) qe[i*4+1] = v4.y;
                    if (i * 4 + 2 < 31) qe[i*4+2] = v4.z;
                    if (i * 4 + 3 < 31) qe[i*4+3] = v4.w;
                }
            } else {
                e0 = erow[min(hb, TFR - 1)];
                #pragma unroll
                for (int i = 0; i < 31; ++i)
                    qe[i] = erow[min(hb + 1 + i, TFR - 1)];
            }

            // base emit at hb (always < tend by construction)
            {
                float np = (float)wy8[0][0];
                float expo = -np / (v + EPS_F) * COEF;
                float spp  = 1.f / fmaf(RATIO, __expf(expo), 1.f);
                float d = e0 - spp;
                local = fmaf(d, d, local);
            }
            // updates hb+1 .. hb+32; emits hb+1 .. hb+31 (hb+32 is next base)
            #pragma unroll
            for (int i = 0; i < 32; ++i) {
                float nv = (i < 31) ? (float)wn8[(i + 1) / 8][(i + 1) % 8]
                                    : last_n;
                v = fmaf(alpha, v, oma * nv);
                if (i < 31) {
                    int t = hb + 1 + i;
                    if (t < tend) {
                        float yv = (float)wy8[(i + 1) / 8][(i + 1) % 8];
                        float expo = -yv / (v + EPS_F) * COEF;
                        float spp  = 1.f / fmaf(RATIO, __expf(expo), 1.f);
                        float d = qe[i] - spp;
                        local = fmaf(d, d, local);
                    }
                }
            }
        }
    }

    for (int off = 32; off > 0; off >>= 1)
        local += __shfl_down(local, off);
    __shared__ float wsum[4];
    if ((threadIdx.x & 63) == 0) wsum[threadIdx.x >> 6] = local;
    __syncthreads();
    if (threadIdx.x == 0) {
        float ssum = (wsum[0] + wsum[1]) + (wsum[2] + wsum[3]);
        atomicAdd(out, ssum * INVN);
    }
}

extern "C" void kernel_launch(void* const* d_in, const int* in_sizes, int n_in,
                              void* d_out, int out_size, void* d_ws, size_t ws_size,
                              hipStream_t stream) {
    const float* est  = (const float*)d_in[0];   // spp_estimate (B,1,F,T)
    const float* sig  = (const float*)d_in[1];   // input_sig    (B,1,N)
    const float* intf = (const float*)d_in[2];   // interference (B,1,N)

    unsigned short* Bt = (unsigned short*)d_ws;                       // 256 KB
    float* wtab = (float*)((char*)d_ws + (size_t)262144);             // 2 KB
    _Float16* powp = (_Float16*)((char*)d_ws + (size_t)512 * 1024);

    hipLaunchKernelGGL(build_basis, dim3(128), dim3(256), 0, stream,
                       Bt, wtab, (float*)d_out);

    hipFuncSetAttribute((const void*)dft_gemm,
                        hipFuncAttributeMaxDynamicSharedMemorySize, LDS_TOTAL);
    dim3 gG(8, 64, 2);
    hipLaunchKernelGGL(dft_gemm, gG, dim3(512), LDS_TOTAL, stream,
                       sig, intf, Bt, wtab, powp);

    const double alpha_d = exp(-((double)256) / (16000.0 * 0.072));
    const _Float16* noiseP = powp;                            // sb 0..63
    const _Float16* noisyP = powp + (size_t)B_SZ * FPOW * TP; // sb 64..127
    dim3 gB((B_SZ * NCH * NF + 255) / 256);
    hipLaunchKernelGGL(spp_loss_kernel, gB, dim3(256), 0, stream,
                       noiseP, noisyP, est, (float*)d_out, (float)alpha_d);
}